// Round 6
// baseline (213.041 us; speedup 1.0000x reference)
//
#include <hip/hip_runtime.h>
#include <hip/hip_bf16.h>

constexpr int PAD_T = 10, BOS_T = 11, EOS_T = 12, ROW_T = 13, SEP_T = 14;
constexpr int Bc = 16, Tc = 4096, Dc = 512;
constexpr int MAXH = 30, MAXW = 30;

typedef float fvec4 __attribute__((ext_vector_type(4)));

// Scratch in module-scope device globals (the d_ws poison is unconditional,
// so d_ws is unused entirely). scan_pre_kernel fully rewrites all three
// every launch before fuse_ln_kernel reads them: no stale-data hazard.
__device__ __align__(16) int   g_packed[Bc * Tc];        // 256 KiB
__device__ __align__(16) float g_frow[MAXH * Dc];        // 60 KiB
__device__ __align__(16) float g_fcol[MAXW * Dc];        // 60 KiB

// Composable transition summary of a token chunk.
struct Summ { int r, c0, c1, g0, g1, rk, ck; };

__device__ inline void tok_update(int tok, Summ& s) {
    if (tok == BOS_T)      { s.g0 = 1; s.g1 = 1; s.r = 0; s.c0 = 0; s.c1 = 0; s.rk = 0; s.ck = 0; }
    else if (tok == SEP_T) { s.r = 0; s.c0 = 0; s.c1 = 0; s.rk = 0; s.ck = 0; }
    else if (tok == ROW_T) { s.r += 1; s.c0 = 0; s.c1 = 0; s.ck = 0; }
    else if (tok == EOS_T || tok == PAD_T) { s.g0 = 0; s.g1 = 0; }
    else { s.c0 += s.g0; s.c1 += s.g1; }   // digit 0..9
}

__device__ inline Summ compose(const Summ& a, const Summ& b) {
    Summ o;
    o.g0 = a.g0 ? b.g1 : b.g0;
    o.g1 = a.g1 ? b.g1 : b.g0;
    o.r  = b.rk ? a.r + b.r : b.r;
    o.rk = a.rk & b.rk;
    int cm0 = a.g0 ? b.c1 : b.c0;
    int cm1 = a.g1 ? b.c1 : b.c0;
    o.c0 = b.ck ? a.c0 + cm0 : cm0;
    o.c1 = b.ck ? a.c1 + cm1 : cm1;
    o.ck = a.ck & b.ck;
    return o;
}

__device__ inline void apply_state(const Summ& s, int& r, int& c, int& g) {
    int cm = g ? s.c1 : s.c0;
    r = s.rk ? r + s.r : s.r;
    c = s.ck ? c + cm : cm;
    g = g ? s.g1 : s.g0;
}

// ---------------------------------------------------------------------------
// Dispatch 1 (merged): blocks 0..15 = parallel automaton scan; blocks 16..75 =
// einsum collapse Frow = row_table @ W[:, :256]^T, Fcol = col_table @ W[:, 256:]^T.
// ---------------------------------------------------------------------------
__global__ __launch_bounds__(1024) void scan_pre_kernel(
        const int* __restrict__ ids,
        const float* __restrict__ row_table, const float* __restrict__ col_table,
        const float* __restrict__ w) {
    if (blockIdx.x < 16) {
        const int b = blockIdx.x;
        const int tid = threadIdx.x;          // 0..1023
        const int lane = tid & 63, wid = tid >> 6;

        const int4 tk4 = *(const int4*)(ids + b * Tc + tid * 4);
        int tks[4] = {tk4.x, tk4.y, tk4.z, tk4.w};

        Summ s{0, 0, 0, 0, 1, 1, 1};
#pragma unroll
        for (int j = 0; j < 4; ++j) tok_update(tks[j], s);

        Summ inc = s;
#pragma unroll
        for (int d = 1; d < 64; d <<= 1) {
            Summ o;
            o.r  = __shfl_up(inc.r, d);
            o.c0 = __shfl_up(inc.c0, d);
            o.c1 = __shfl_up(inc.c1, d);
            o.g0 = __shfl_up(inc.g0, d);
            o.g1 = __shfl_up(inc.g1, d);
            o.rk = __shfl_up(inc.rk, d);
            o.ck = __shfl_up(inc.ck, d);
            if (lane >= d) inc = compose(o, inc);
        }

        __shared__ int lsum[16][7];
        if (lane == 63) {
            lsum[wid][0] = inc.r;  lsum[wid][1] = inc.c0; lsum[wid][2] = inc.c1;
            lsum[wid][3] = inc.g0; lsum[wid][4] = inc.g1;
            lsum[wid][5] = inc.rk; lsum[wid][6] = inc.ck;
        }
        __syncthreads();

        int wr = 0, wc = 0, wg = 0;
        for (int w2 = 0; w2 < wid; ++w2) {
            Summ t;
            t.r  = lsum[w2][0]; t.c0 = lsum[w2][1]; t.c1 = lsum[w2][2];
            t.g0 = lsum[w2][3]; t.g1 = lsum[w2][4];
            t.rk = lsum[w2][5]; t.ck = lsum[w2][6];
            apply_state(t, wr, wc, wg);
        }

        Summ ex;
        ex.r  = __shfl_up(inc.r, 1);  ex.c0 = __shfl_up(inc.c0, 1);
        ex.c1 = __shfl_up(inc.c1, 1); ex.g0 = __shfl_up(inc.g0, 1);
        ex.g1 = __shfl_up(inc.g1, 1); ex.rk = __shfl_up(inc.rk, 1);
        ex.ck = __shfl_up(inc.ck, 1);
        if (lane == 0) { ex = Summ{0, 0, 0, 0, 1, 1, 1}; }
        int row = wr, col = wc, grid = wg;
        apply_state(ex, row, col, grid);

        int o4[4];
#pragma unroll
        for (int j = 0; j < 4; ++j) {
            int tok = tks[j];
            int gc = grid & (tok <= 9);
            int er = gc ? min(row, MAXH - 1) : 0;
            int ec = gc ? min(col, MAXW - 1) : 0;
            o4[j] = (er << 5) | ec;
            if (tok == BOS_T)      { grid = 1; row = 0; col = 0; }
            else if (tok == SEP_T) { row = 0; col = 0; }
            else if (tok == ROW_T) { row += 1; col = 0; }
            else if (tok == EOS_T || tok == PAD_T) { grid = 0; }
            else { col += gc; }
        }
        *(int4*)(g_packed + b * Tc + tid * 4) = make_int4(o4[0], o4[1], o4[2], o4[3]);
    } else {
        const int blk = blockIdx.x - 16;
        const int which = blk / 30;            // 0 -> Frow, 1 -> Fcol
        const int rr = blk % 30;
        const float* src = which ? (col_table + rr * 256) : (row_table + rr * 256);
        float* dst = which ? (g_fcol + rr * Dc) : (g_frow + rr * Dc);
        const int doff = which ? 256 : 0;

        __shared__ __align__(16) float sv[256];
        __shared__ float part[512];
        if (threadIdx.x < 256) sv[threadIdx.x] = src[threadIdx.x];
        __syncthreads();

        const int e    = threadIdx.x & 511;
        const int half = threadIdx.x >> 9;     // split-k: 2 threads per output
        const float4* a4 = (const float4*)sv + half * 32;
        const float4* w4 = (const float4*)(w + (size_t)e * Dc + doff) + half * 32;
        float acc = 0.f;
#pragma unroll 8
        for (int k = 0; k < 32; ++k) {
            float4 a = a4[k];
            float4 wb = w4[k];
            acc += a.x * wb.x + a.y * wb.y + a.z * wb.z + a.w * wb.w;
        }
        if (half) part[e] = acc;
        __syncthreads();
        if (!half) dst[e] = acc + part[e];
    }
}

// ---------------------------------------------------------------------------
// Dispatch 2: fused embed-add + LayerNorm. PERSISTENT waves: 8192 waves,
// each loops over 4 (t,b0) groups (2 rows/group: b0 and b0+8, shared pos),
// prefetching next group's ids/packed/pos one iteration ahead -- the only
// HBM-latency read (pos) hides across the loop boundary. gamma/beta are
// reloaded per iteration in 4-float chunks (L1-resident) instead of held
// resident: trims ~16 persistent VGPRs for occupancy. launch_bounds(256,6)
// requests 6 waves/SIMD (was ~4). Cached stores (NT amplifies: round 2).
// ---------------------------------------------------------------------------
__global__ __launch_bounds__(256, 6) void fuse_ln_kernel(
        const int* __restrict__ ids,
        const float* __restrict__ token_table, const float* __restrict__ pos_table,
        const float* __restrict__ gamma, const float* __restrict__ beta,
        float* __restrict__ out) {
    const int wave = threadIdx.x >> 6;
    const int lane = threadIdx.x & 63;
    const int d0 = lane * 8;
    const int g0 = blockIdx.x * 4 + wave;     // wave id in [0, 8192)
    constexpr int WAVES = 2048 * 4;           // grid waves
    constexpr int NITER = (8 * Tc) / WAVES;   // 4

    // ---- prefetch iteration 0 ----
    int g = g0;
    int idx0 = (g & 7) * Tc + (g >> 3);       // (b0, t)
    int tk0 = ids[idx0];
    int tk1 = ids[idx0 + 8 * Tc];
    int pk0 = g_packed[idx0];
    int pk1 = g_packed[idx0 + 8 * Tc];
    float xp[8];
    {
        const float* p = pos_table + (size_t)(g >> 3) * Dc + d0;
        *(float4*)(xp + 0) = *(const float4*)(p);
        *(float4*)(xp + 4) = *(const float4*)(p + 4);
    }

#pragma unroll 1
    for (int it = 0; it < NITER; ++it) {
        // ---- issue next iteration's independent loads first ----
        int ntk0 = 0, ntk1 = 0, npk0 = 0, npk1 = 0, nidx0 = 0;
        float nxp[8];
        if (it + 1 < NITER) {
            const int ng = g + WAVES;
            nidx0 = (ng & 7) * Tc + (ng >> 3);
            ntk0 = ids[nidx0];
            ntk1 = ids[nidx0 + 8 * Tc];
            npk0 = g_packed[nidx0];
            npk1 = g_packed[nidx0 + 8 * Tc];
            const float* p = pos_table + (size_t)(ng >> 3) * Dc + d0;
            *(float4*)(nxp + 0) = *(const float4*)(p);
            *(float4*)(nxp + 4) = *(const float4*)(p + 4);
        }

        // ---- current group: 2 rows (b0,t) and (b0+8,t) ----
        const int idx1 = idx0 + 8 * Tc;
        float x0[8], x1[8];
        {
            const float* tr = token_table + (size_t)tk0 * Dc + d0;
            float4 va = *(const float4*)(tr);
            float4 vb = *(const float4*)(tr + 4);
            x0[0] = va.x + xp[0]; x0[1] = va.y + xp[1];
            x0[2] = va.z + xp[2]; x0[3] = va.w + xp[3];
            x0[4] = vb.x + xp[4]; x0[5] = vb.y + xp[5];
            x0[6] = vb.z + xp[6]; x0[7] = vb.w + xp[7];
        }
        {
            const float* tr = token_table + (size_t)tk1 * Dc + d0;
            float4 va = *(const float4*)(tr);
            float4 vb = *(const float4*)(tr + 4);
            x1[0] = va.x + xp[0]; x1[1] = va.y + xp[1];
            x1[2] = va.z + xp[2]; x1[3] = va.w + xp[3];
            x1[4] = vb.x + xp[4]; x1[5] = vb.y + xp[5];
            x1[6] = vb.z + xp[6]; x1[7] = vb.w + xp[7];
        }
        if (tk0 <= 9) {                       // wave-uniform
            const int rI = pk0 >> 5, cI = pk0 & 31;
            const float* fr = g_frow + (size_t)rI * Dc + d0;
            const float* fc = g_fcol + (size_t)cI * Dc + d0;
            float4 ra = *(const float4*)(fr);
            float4 rb = *(const float4*)(fr + 4);
            float4 ca = *(const float4*)(fc);
            float4 cb = *(const float4*)(fc + 4);
            x0[0] += ra.x + ca.x; x0[1] += ra.y + ca.y;
            x0[2] += ra.z + ca.z; x0[3] += ra.w + ca.w;
            x0[4] += rb.x + cb.x; x0[5] += rb.y + cb.y;
            x0[6] += rb.z + cb.z; x0[7] += rb.w + cb.w;
        }
        if (tk1 <= 9) {                       // wave-uniform
            const int rI = pk1 >> 5, cI = pk1 & 31;
            const float* fr = g_frow + (size_t)rI * Dc + d0;
            const float* fc = g_fcol + (size_t)cI * Dc + d0;
            float4 ra = *(const float4*)(fr);
            float4 rb = *(const float4*)(fr + 4);
            float4 ca = *(const float4*)(fc);
            float4 cb = *(const float4*)(fc + 4);
            x1[0] += ra.x + ca.x; x1[1] += ra.y + ca.y;
            x1[2] += ra.z + ca.z; x1[3] += ra.w + ca.w;
            x1[4] += rb.x + cb.x; x1[5] += rb.y + cb.y;
            x1[6] += rb.z + cb.z; x1[7] += rb.w + cb.w;
        }

        float s0 = 0.f, q0 = 0.f, s1 = 0.f, q1 = 0.f;
#pragma unroll
        for (int j = 0; j < 8; ++j) {
            s0 += x0[j]; q0 = fmaf(x0[j], x0[j], q0);
            s1 += x1[j]; q1 = fmaf(x1[j], x1[j], q1);
        }
#pragma unroll
        for (int m = 1; m < 64; m <<= 1) {
            s0 += __shfl_xor(s0, m);
            s1 += __shfl_xor(s1, m);
            q0 += __shfl_xor(q0, m);
            q1 += __shfl_xor(q1, m);
        }
        const float mu0  = s0 * (1.0f / Dc);
        const float mu1  = s1 * (1.0f / Dc);
        const float inv0 = rsqrtf(fmaf(-mu0, mu0, q0 * (1.0f / Dc)) + 1e-5f);
        const float inv1 = rsqrtf(fmaf(-mu1, mu1, q1 * (1.0f / Dc)) + 1e-5f);

        // normalize + store, gamma/beta reloaded per 4-chunk (L1-resident)
        float* op0 = out + (size_t)idx0 * Dc + d0;
        float* op1 = out + (size_t)idx1 * Dc + d0;
#pragma unroll
        for (int q = 0; q < 2; ++q) {
            float4 g4 = *(const float4*)(gamma + d0 + 4 * q);
            float4 b4 = *(const float4*)(beta + d0 + 4 * q);
            fvec4 y0, y1;
            y0.x = fmaf((x0[4 * q + 0] - mu0) * inv0, g4.x, b4.x);
            y0.y = fmaf((x0[4 * q + 1] - mu0) * inv0, g4.y, b4.y);
            y0.z = fmaf((x0[4 * q + 2] - mu0) * inv0, g4.z, b4.z);
            y0.w = fmaf((x0[4 * q + 3] - mu0) * inv0, g4.w, b4.w);
            y1.x = fmaf((x1[4 * q + 0] - mu1) * inv1, g4.x, b4.x);
            y1.y = fmaf((x1[4 * q + 1] - mu1) * inv1, g4.y, b4.y);
            y1.z = fmaf((x1[4 * q + 2] - mu1) * inv1, g4.z, b4.z);
            y1.w = fmaf((x1[4 * q + 3] - mu1) * inv1, g4.w, b4.w);
            *(fvec4*)(op0 + 4 * q) = y0;
            *(fvec4*)(op1 + 4 * q) = y1;
        }

        // ---- rotate prefetched state ----
        g += WAVES;
        idx0 = nidx0;
        tk0 = ntk0; tk1 = ntk1; pk0 = npk0; pk1 = npk1;
#pragma unroll
        for (int j = 0; j < 8; ++j) xp[j] = nxp[j];
    }
}

extern "C" void kernel_launch(void* const* d_in, const int* in_sizes, int n_in,
                              void* d_out, int out_size, void* d_ws, size_t ws_size,
                              hipStream_t stream) {
    const int*   ids         = (const int*)d_in[0];
    const float* token_table = (const float*)d_in[1];
    const float* pos_table   = (const float*)d_in[2];
    const float* row_table   = (const float*)d_in[3];
    const float* col_table   = (const float*)d_in[4];
    const float* w_spatial   = (const float*)d_in[5];
    const float* ln_gamma    = (const float*)d_in[6];
    const float* ln_beta     = (const float*)d_in[7];
    float* out = (float*)d_out;

    (void)d_ws; (void)ws_size;   // ws poison is unconditional; we don't add to it

    hipLaunchKernelGGL(scan_pre_kernel, dim3(76), dim3(1024), 0, stream,
                       ids, row_table, col_table, w_spatial);
    hipLaunchKernelGGL(fuse_ln_kernel, dim3(2048), dim3(256), 0, stream,
                       ids, token_table, pos_table, ln_gamma, ln_beta, out);
}

// Round 7
// 193.791 us; speedup vs baseline: 1.0993x; 1.0993x over previous
//
#include <hip/hip_runtime.h>
#include <hip/hip_bf16.h>

constexpr int PAD_T = 10, BOS_T = 11, EOS_T = 12, ROW_T = 13, SEP_T = 14;
constexpr int Bc = 16, Tc = 4096, Dc = 512;
constexpr int MAXH = 30, MAXW = 30;

typedef float fvec4 __attribute__((ext_vector_type(4)));

// Scratch in module-scope device globals (the d_ws poison is unconditional,
// so d_ws is unused entirely). scan_pre_kernel fully rewrites all three
// every launch before fuse_ln_kernel reads them: no stale-data hazard.
__device__ __align__(16) int   g_packed[Bc * Tc];        // 256 KiB
__device__ __align__(16) float g_frow[MAXH * Dc];        // 60 KiB
__device__ __align__(16) float g_fcol[MAXW * Dc];        // 60 KiB

// Composable transition summary of a token chunk.
struct Summ { int r, c0, c1, g0, g1, rk, ck; };

__device__ inline void tok_update(int tok, Summ& s) {
    if (tok == BOS_T)      { s.g0 = 1; s.g1 = 1; s.r = 0; s.c0 = 0; s.c1 = 0; s.rk = 0; s.ck = 0; }
    else if (tok == SEP_T) { s.r = 0; s.c0 = 0; s.c1 = 0; s.rk = 0; s.ck = 0; }
    else if (tok == ROW_T) { s.r += 1; s.c0 = 0; s.c1 = 0; s.ck = 0; }
    else if (tok == EOS_T || tok == PAD_T) { s.g0 = 0; s.g1 = 0; }
    else { s.c0 += s.g0; s.c1 += s.g1; }   // digit 0..9
}

__device__ inline Summ compose(const Summ& a, const Summ& b) {
    Summ o;
    o.g0 = a.g0 ? b.g1 : b.g0;
    o.g1 = a.g1 ? b.g1 : b.g0;
    o.r  = b.rk ? a.r + b.r : b.r;
    o.rk = a.rk & b.rk;
    int cm0 = a.g0 ? b.c1 : b.c0;
    int cm1 = a.g1 ? b.c1 : b.c0;
    o.c0 = b.ck ? a.c0 + cm0 : cm0;
    o.c1 = b.ck ? a.c1 + cm1 : cm1;
    o.ck = a.ck & b.ck;
    return o;
}

__device__ inline void apply_state(const Summ& s, int& r, int& c, int& g) {
    int cm = g ? s.c1 : s.c0;
    r = s.rk ? r + s.r : s.r;
    c = s.ck ? c + cm : cm;
    g = g ? s.g1 : s.g0;
}

// ---------------------------------------------------------------------------
// Dispatch 1 (merged): blocks 0..15 = parallel automaton scan; blocks 16..75 =
// einsum collapse Frow = row_table @ W[:, :256]^T, Fcol = col_table @ W[:, 256:]^T.
// ---------------------------------------------------------------------------
__global__ __launch_bounds__(1024) void scan_pre_kernel(
        const int* __restrict__ ids,
        const float* __restrict__ row_table, const float* __restrict__ col_table,
        const float* __restrict__ w) {
    if (blockIdx.x < 16) {
        const int b = blockIdx.x;
        const int tid = threadIdx.x;          // 0..1023
        const int lane = tid & 63, wid = tid >> 6;

        const int4 tk4 = *(const int4*)(ids + b * Tc + tid * 4);
        int tks[4] = {tk4.x, tk4.y, tk4.z, tk4.w};

        Summ s{0, 0, 0, 0, 1, 1, 1};
#pragma unroll
        for (int j = 0; j < 4; ++j) tok_update(tks[j], s);

        Summ inc = s;
#pragma unroll
        for (int d = 1; d < 64; d <<= 1) {
            Summ o;
            o.r  = __shfl_up(inc.r, d);
            o.c0 = __shfl_up(inc.c0, d);
            o.c1 = __shfl_up(inc.c1, d);
            o.g0 = __shfl_up(inc.g0, d);
            o.g1 = __shfl_up(inc.g1, d);
            o.rk = __shfl_up(inc.rk, d);
            o.ck = __shfl_up(inc.ck, d);
            if (lane >= d) inc = compose(o, inc);
        }

        __shared__ int lsum[16][7];
        if (lane == 63) {
            lsum[wid][0] = inc.r;  lsum[wid][1] = inc.c0; lsum[wid][2] = inc.c1;
            lsum[wid][3] = inc.g0; lsum[wid][4] = inc.g1;
            lsum[wid][5] = inc.rk; lsum[wid][6] = inc.ck;
        }
        __syncthreads();

        int wr = 0, wc = 0, wg = 0;
        for (int w2 = 0; w2 < wid; ++w2) {
            Summ t;
            t.r  = lsum[w2][0]; t.c0 = lsum[w2][1]; t.c1 = lsum[w2][2];
            t.g0 = lsum[w2][3]; t.g1 = lsum[w2][4];
            t.rk = lsum[w2][5]; t.ck = lsum[w2][6];
            apply_state(t, wr, wc, wg);
        }

        Summ ex;
        ex.r  = __shfl_up(inc.r, 1);  ex.c0 = __shfl_up(inc.c0, 1);
        ex.c1 = __shfl_up(inc.c1, 1); ex.g0 = __shfl_up(inc.g0, 1);
        ex.g1 = __shfl_up(inc.g1, 1); ex.rk = __shfl_up(inc.rk, 1);
        ex.ck = __shfl_up(inc.ck, 1);
        if (lane == 0) { ex = Summ{0, 0, 0, 0, 1, 1, 1}; }
        int row = wr, col = wc, grid = wg;
        apply_state(ex, row, col, grid);

        int o4[4];
#pragma unroll
        for (int j = 0; j < 4; ++j) {
            int tok = tks[j];
            int gc = grid & (tok <= 9);
            int er = gc ? min(row, MAXH - 1) : 0;
            int ec = gc ? min(col, MAXW - 1) : 0;
            o4[j] = (er << 5) | ec;
            if (tok == BOS_T)      { grid = 1; row = 0; col = 0; }
            else if (tok == SEP_T) { row = 0; col = 0; }
            else if (tok == ROW_T) { row += 1; col = 0; }
            else if (tok == EOS_T || tok == PAD_T) { grid = 0; }
            else { col += gc; }
        }
        *(int4*)(g_packed + b * Tc + tid * 4) = make_int4(o4[0], o4[1], o4[2], o4[3]);
    } else {
        const int blk = blockIdx.x - 16;
        const int which = blk / 30;            // 0 -> Frow, 1 -> Fcol
        const int rr = blk % 30;
        const float* src = which ? (col_table + rr * 256) : (row_table + rr * 256);
        float* dst = which ? (g_fcol + rr * Dc) : (g_frow + rr * Dc);
        const int doff = which ? 256 : 0;

        __shared__ __align__(16) float sv[256];
        __shared__ float part[512];
        if (threadIdx.x < 256) sv[threadIdx.x] = src[threadIdx.x];
        __syncthreads();

        const int e    = threadIdx.x & 511;
        const int half = threadIdx.x >> 9;     // split-k: 2 threads per output
        const float4* a4 = (const float4*)sv + half * 32;
        const float4* w4 = (const float4*)(w + (size_t)e * Dc + doff) + half * 32;
        float acc = 0.f;
#pragma unroll 8
        for (int k = 0; k < 32; ++k) {
            float4 a = a4[k];
            float4 wb = w4[k];
            acc += a.x * wb.x + a.y * wb.y + a.z * wb.z + a.w * wb.w;
        }
        if (half) part[e] = acc;
        __syncthreads();
        if (!half) dst[e] = acc + part[e];
    }
}

// ---------------------------------------------------------------------------
// Dispatch 2: fused embed-add + LayerNorm. EIGHT tokens concurrently in
// flight per wave: (b0, b0+8) x (t..t+3), one-shot (no loop-carried state;
// round 6 showed persistent/serialized epochs lose to raw concurrency).
// ids/packed are int4 loads (4 tokens per instruction); 4 pos rows shared
// across the two batch rows; 16 butterfly chains interleaved; stores form
// two contiguous 8KB runs. Cached stores (NT amplifies: round 2).
// ---------------------------------------------------------------------------
__global__ __launch_bounds__(256) void fuse_ln_kernel(
        const int* __restrict__ ids,
        const float* __restrict__ token_table, const float* __restrict__ pos_table,
        const float* __restrict__ gamma, const float* __restrict__ beta,
        float* __restrict__ out) {
    const int wave = threadIdx.x >> 6;
    const int lane = threadIdx.x & 63;
    const int d0 = lane * 8;
    const int g = blockIdx.x * 4 + wave;      // wave id in [0, 8192)
    const int b0 = g & 7;
    const int t  = (g >> 3) << 2;             // wave covers t..t+3
    const int idxA = b0 * Tc + t;             // rows (b0,   t..t+3)
    const int idxB = idxA + 8 * Tc;           // rows (b0+8, t..t+3)

    // 4 tokens per int4 load — all index data in 4 instructions
    const int4 tkA = *(const int4*)(ids + idxA);
    const int4 tkB = *(const int4*)(ids + idxB);
    const int4 pkA = *(const int4*)(g_packed + idxA);
    const int4 pkB = *(const int4*)(g_packed + idxB);
    const int tA[4] = {tkA.x, tkA.y, tkA.z, tkA.w};
    const int tB[4] = {tkB.x, tkB.y, tkB.z, tkB.w};
    const int pA[4] = {pkA.x, pkA.y, pkA.z, pkA.w};
    const int pB[4] = {pkB.x, pkB.y, pkB.z, pkB.w};

    // pos rows t..t+3 (streamed from HBM — the long-latency reads, issued early)
    float xp0[8], xp1[8], xp2[8], xp3[8];
    {
        const float* p = pos_table + (size_t)t * Dc + d0;
        *(float4*)(xp0 + 0) = *(const float4*)(p);
        *(float4*)(xp0 + 4) = *(const float4*)(p + 4);
        *(float4*)(xp1 + 0) = *(const float4*)(p + Dc);
        *(float4*)(xp1 + 4) = *(const float4*)(p + Dc + 4);
        *(float4*)(xp2 + 0) = *(const float4*)(p + 2 * Dc);
        *(float4*)(xp2 + 4) = *(const float4*)(p + 2 * Dc + 4);
        *(float4*)(xp3 + 0) = *(const float4*)(p + 3 * Dc);
        *(float4*)(xp3 + 4) = *(const float4*)(p + 3 * Dc + 4);
    }

    float gm[8], bt[8];
    *(float4*)(gm + 0) = *(const float4*)(gamma + d0);
    *(float4*)(gm + 4) = *(const float4*)(gamma + d0 + 4);
    *(float4*)(bt + 0) = *(const float4*)(beta + d0);
    *(float4*)(bt + 4) = *(const float4*)(beta + d0 + 4);

    float xA0[8], xA1[8], xA2[8], xA3[8];
    float xB0[8], xB1[8], xB2[8], xB3[8];

    auto load_tok = [&](float* dst, int tok, const float* xp) {
        const float* tr = token_table + (size_t)tok * Dc + d0;
        float4 va = *(const float4*)(tr);
        float4 vb = *(const float4*)(tr + 4);
        dst[0] = va.x + xp[0]; dst[1] = va.y + xp[1];
        dst[2] = va.z + xp[2]; dst[3] = va.w + xp[3];
        dst[4] = vb.x + xp[4]; dst[5] = vb.y + xp[5];
        dst[6] = vb.z + xp[6]; dst[7] = vb.w + xp[7];
    };
    load_tok(xA0, tA[0], xp0); load_tok(xA1, tA[1], xp1);
    load_tok(xA2, tA[2], xp2); load_tok(xA3, tA[3], xp3);
    load_tok(xB0, tB[0], xp0); load_tok(xB1, tB[1], xp1);
    load_tok(xB2, tB[2], xp2); load_tok(xB3, tB[3], xp3);

    auto add_spatial = [&](float* dst, int tok, int pk) {
        if (tok <= 9) {                       // wave-uniform branch
            const int rI = pk >> 5, cI = pk & 31;
            const float* fr = g_frow + (size_t)rI * Dc + d0;
            const float* fc = g_fcol + (size_t)cI * Dc + d0;
            float4 ra = *(const float4*)(fr);
            float4 rb = *(const float4*)(fr + 4);
            float4 ca = *(const float4*)(fc);
            float4 cb = *(const float4*)(fc + 4);
            dst[0] += ra.x + ca.x; dst[1] += ra.y + ca.y;
            dst[2] += ra.z + ca.z; dst[3] += ra.w + ca.w;
            dst[4] += rb.x + cb.x; dst[5] += rb.y + cb.y;
            dst[6] += rb.z + cb.z; dst[7] += rb.w + cb.w;
        }
    };
    add_spatial(xA0, tA[0], pA[0]); add_spatial(xA1, tA[1], pA[1]);
    add_spatial(xA2, tA[2], pA[2]); add_spatial(xA3, tA[3], pA[3]);
    add_spatial(xB0, tB[0], pB[0]); add_spatial(xB1, tB[1], pB[1]);
    add_spatial(xB2, tB[2], pB[2]); add_spatial(xB3, tB[3], pB[3]);

    // per-lane partial sums: 16 accumulators (8 rows x {sum, sumsq})
    float sA0 = 0.f, qA0 = 0.f, sA1 = 0.f, qA1 = 0.f;
    float sA2 = 0.f, qA2 = 0.f, sA3 = 0.f, qA3 = 0.f;
    float sB0 = 0.f, qB0 = 0.f, sB1 = 0.f, qB1 = 0.f;
    float sB2 = 0.f, qB2 = 0.f, sB3 = 0.f, qB3 = 0.f;
#pragma unroll
    for (int j = 0; j < 8; ++j) {
        sA0 += xA0[j]; qA0 = fmaf(xA0[j], xA0[j], qA0);
        sA1 += xA1[j]; qA1 = fmaf(xA1[j], xA1[j], qA1);
        sA2 += xA2[j]; qA2 = fmaf(xA2[j], xA2[j], qA2);
        sA3 += xA3[j]; qA3 = fmaf(xA3[j], xA3[j], qA3);
        sB0 += xB0[j]; qB0 = fmaf(xB0[j], xB0[j], qB0);
        sB1 += xB1[j]; qB1 = fmaf(xB1[j], xB1[j], qB1);
        sB2 += xB2[j]; qB2 = fmaf(xB2[j], xB2[j], qB2);
        sB3 += xB3[j]; qB3 = fmaf(xB3[j], xB3[j], qB3);
    }
    // 16 independent butterfly chains interleaved
#pragma unroll
    for (int m = 1; m < 64; m <<= 1) {
        sA0 += __shfl_xor(sA0, m); sA1 += __shfl_xor(sA1, m);
        sA2 += __shfl_xor(sA2, m); sA3 += __shfl_xor(sA3, m);
        sB0 += __shfl_xor(sB0, m); sB1 += __shfl_xor(sB1, m);
        sB2 += __shfl_xor(sB2, m); sB3 += __shfl_xor(sB3, m);
        qA0 += __shfl_xor(qA0, m); qA1 += __shfl_xor(qA1, m);
        qA2 += __shfl_xor(qA2, m); qA3 += __shfl_xor(qA3, m);
        qB0 += __shfl_xor(qB0, m); qB1 += __shfl_xor(qB1, m);
        qB2 += __shfl_xor(qB2, m); qB3 += __shfl_xor(qB3, m);
    }

    auto fin = [](float s, float q, float& mu, float& inv) {
        mu = s * (1.0f / Dc);
        inv = rsqrtf(fmaf(-mu, mu, q * (1.0f / Dc)) + 1e-5f);
    };
    float muA0, ivA0, muA1, ivA1, muA2, ivA2, muA3, ivA3;
    float muB0, ivB0, muB1, ivB1, muB2, ivB2, muB3, ivB3;
    fin(sA0, qA0, muA0, ivA0); fin(sA1, qA1, muA1, ivA1);
    fin(sA2, qA2, muA2, ivA2); fin(sA3, qA3, muA3, ivA3);
    fin(sB0, qB0, muB0, ivB0); fin(sB1, qB1, muB1, ivB1);
    fin(sB2, qB2, muB2, ivB2); fin(sB3, qB3, muB3, ivB3);

    auto store_row = [&](const float* v, float mu, float inv, int base) {
        fvec4 ya, yb;
        ya.x = fmaf((v[0] - mu) * inv, gm[0], bt[0]);
        ya.y = fmaf((v[1] - mu) * inv, gm[1], bt[1]);
        ya.z = fmaf((v[2] - mu) * inv, gm[2], bt[2]);
        ya.w = fmaf((v[3] - mu) * inv, gm[3], bt[3]);
        yb.x = fmaf((v[4] - mu) * inv, gm[4], bt[4]);
        yb.y = fmaf((v[5] - mu) * inv, gm[5], bt[5]);
        yb.z = fmaf((v[6] - mu) * inv, gm[6], bt[6]);
        yb.w = fmaf((v[7] - mu) * inv, gm[7], bt[7]);
        float* op = out + (size_t)base * Dc + d0;
        *(fvec4*)(op + 0) = ya;
        *(fvec4*)(op + 4) = yb;
    };
    // two contiguous 8KB runs per wave
    store_row(xA0, muA0, ivA0, idxA);
    store_row(xA1, muA1, ivA1, idxA + 1);
    store_row(xA2, muA2, ivA2, idxA + 2);
    store_row(xA3, muA3, ivA3, idxA + 3);
    store_row(xB0, muB0, ivB0, idxB);
    store_row(xB1, muB1, ivB1, idxB + 1);
    store_row(xB2, muB2, ivB2, idxB + 2);
    store_row(xB3, muB3, ivB3, idxB + 3);
}

extern "C" void kernel_launch(void* const* d_in, const int* in_sizes, int n_in,
                              void* d_out, int out_size, void* d_ws, size_t ws_size,
                              hipStream_t stream) {
    const int*   ids         = (const int*)d_in[0];
    const float* token_table = (const float*)d_in[1];
    const float* pos_table   = (const float*)d_in[2];
    const float* row_table   = (const float*)d_in[3];
    const float* col_table   = (const float*)d_in[4];
    const float* w_spatial   = (const float*)d_in[5];
    const float* ln_gamma    = (const float*)d_in[6];
    const float* ln_beta     = (const float*)d_in[7];
    float* out = (float*)d_out;

    (void)d_ws; (void)ws_size;   // ws poison is unconditional; we don't add to it

    hipLaunchKernelGGL(scan_pre_kernel, dim3(76), dim3(1024), 0, stream,
                       ids, row_table, col_table, w_spatial);
    hipLaunchKernelGGL(fuse_ln_kernel, dim3(2048), dim3(256), 0, stream,
                       ids, token_table, pos_table, ln_gamma, ln_beta, out);
}

// Round 8
// 186.869 us; speedup vs baseline: 1.1401x; 1.0370x over previous
//
#include <hip/hip_runtime.h>
#include <hip/hip_bf16.h>

constexpr int PAD_T = 10, BOS_T = 11, EOS_T = 12, ROW_T = 13, SEP_T = 14;
constexpr int Bc = 16, Tc = 4096, Dc = 512;
constexpr int MAXH = 30, MAXW = 30;

typedef float fvec4 __attribute__((ext_vector_type(4)));

// Scratch in module-scope device globals (the d_ws poison is unconditional,
// so d_ws is unused entirely). scan_pre_kernel fully rewrites all three
// every launch before fuse_ln_kernel reads them: no stale-data hazard.
__device__ __align__(16) int   g_packed[Bc * Tc];        // 256 KiB
__device__ __align__(16) float g_frow[MAXH * Dc];        // 60 KiB
__device__ __align__(16) float g_fcol[MAXW * Dc];        // 60 KiB

// Composable transition summary of a token chunk.
struct Summ { int r, c0, c1, g0, g1, rk, ck; };

__device__ inline void tok_update(int tok, Summ& s) {
    if (tok == BOS_T)      { s.g0 = 1; s.g1 = 1; s.r = 0; s.c0 = 0; s.c1 = 0; s.rk = 0; s.ck = 0; }
    else if (tok == SEP_T) { s.r = 0; s.c0 = 0; s.c1 = 0; s.rk = 0; s.ck = 0; }
    else if (tok == ROW_T) { s.r += 1; s.c0 = 0; s.c1 = 0; s.ck = 0; }
    else if (tok == EOS_T || tok == PAD_T) { s.g0 = 0; s.g1 = 0; }
    else { s.c0 += s.g0; s.c1 += s.g1; }   // digit 0..9
}

__device__ inline Summ compose(const Summ& a, const Summ& b) {
    Summ o;
    o.g0 = a.g0 ? b.g1 : b.g0;
    o.g1 = a.g1 ? b.g1 : b.g0;
    o.r  = b.rk ? a.r + b.r : b.r;
    o.rk = a.rk & b.rk;
    int cm0 = a.g0 ? b.c1 : b.c0;
    int cm1 = a.g1 ? b.c1 : b.c0;
    o.c0 = b.ck ? a.c0 + cm0 : cm0;
    o.c1 = b.ck ? a.c1 + cm1 : cm1;
    o.ck = a.ck & b.ck;
    return o;
}

__device__ inline void apply_state(const Summ& s, int& r, int& c, int& g) {
    int cm = g ? s.c1 : s.c0;
    r = s.rk ? r + s.r : s.r;
    c = s.ck ? c + cm : cm;
    g = g ? s.g1 : s.g0;
}

// ---------------------------------------------------------------------------
// Dispatch 1 (merged): blocks 0..15 = parallel automaton scan; blocks 16..75 =
// einsum collapse Frow = row_table @ W[:, :256]^T, Fcol = col_table @ W[:, 256:]^T.
// ---------------------------------------------------------------------------
__global__ __launch_bounds__(1024) void scan_pre_kernel(
        const int* __restrict__ ids,
        const float* __restrict__ row_table, const float* __restrict__ col_table,
        const float* __restrict__ w) {
    if (blockIdx.x < 16) {
        const int b = blockIdx.x;
        const int tid = threadIdx.x;          // 0..1023
        const int lane = tid & 63, wid = tid >> 6;

        const int4 tk4 = *(const int4*)(ids + b * Tc + tid * 4);
        int tks[4] = {tk4.x, tk4.y, tk4.z, tk4.w};

        Summ s{0, 0, 0, 0, 1, 1, 1};
#pragma unroll
        for (int j = 0; j < 4; ++j) tok_update(tks[j], s);

        Summ inc = s;
#pragma unroll
        for (int d = 1; d < 64; d <<= 1) {
            Summ o;
            o.r  = __shfl_up(inc.r, d);
            o.c0 = __shfl_up(inc.c0, d);
            o.c1 = __shfl_up(inc.c1, d);
            o.g0 = __shfl_up(inc.g0, d);
            o.g1 = __shfl_up(inc.g1, d);
            o.rk = __shfl_up(inc.rk, d);
            o.ck = __shfl_up(inc.ck, d);
            if (lane >= d) inc = compose(o, inc);
        }

        __shared__ int lsum[16][7];
        if (lane == 63) {
            lsum[wid][0] = inc.r;  lsum[wid][1] = inc.c0; lsum[wid][2] = inc.c1;
            lsum[wid][3] = inc.g0; lsum[wid][4] = inc.g1;
            lsum[wid][5] = inc.rk; lsum[wid][6] = inc.ck;
        }
        __syncthreads();

        int wr = 0, wc = 0, wg = 0;
        for (int w2 = 0; w2 < wid; ++w2) {
            Summ t;
            t.r  = lsum[w2][0]; t.c0 = lsum[w2][1]; t.c1 = lsum[w2][2];
            t.g0 = lsum[w2][3]; t.g1 = lsum[w2][4];
            t.rk = lsum[w2][5]; t.ck = lsum[w2][6];
            apply_state(t, wr, wc, wg);
        }

        Summ ex;
        ex.r  = __shfl_up(inc.r, 1);  ex.c0 = __shfl_up(inc.c0, 1);
        ex.c1 = __shfl_up(inc.c1, 1); ex.g0 = __shfl_up(inc.g0, 1);
        ex.g1 = __shfl_up(inc.g1, 1); ex.rk = __shfl_up(inc.rk, 1);
        ex.ck = __shfl_up(inc.ck, 1);
        if (lane == 0) { ex = Summ{0, 0, 0, 0, 1, 1, 1}; }
        int row = wr, col = wc, grid = wg;
        apply_state(ex, row, col, grid);

        int o4[4];
#pragma unroll
        for (int j = 0; j < 4; ++j) {
            int tok = tks[j];
            int gc = grid & (tok <= 9);
            int er = gc ? min(row, MAXH - 1) : 0;
            int ec = gc ? min(col, MAXW - 1) : 0;
            o4[j] = (er << 5) | ec;
            if (tok == BOS_T)      { grid = 1; row = 0; col = 0; }
            else if (tok == SEP_T) { row = 0; col = 0; }
            else if (tok == ROW_T) { row += 1; col = 0; }
            else if (tok == EOS_T || tok == PAD_T) { grid = 0; }
            else { col += gc; }
        }
        *(int4*)(g_packed + b * Tc + tid * 4) = make_int4(o4[0], o4[1], o4[2], o4[3]);
    } else {
        const int blk = blockIdx.x - 16;
        const int which = blk / 30;            // 0 -> Frow, 1 -> Fcol
        const int rr = blk % 30;
        const float* src = which ? (col_table + rr * 256) : (row_table + rr * 256);
        float* dst = which ? (g_fcol + rr * Dc) : (g_frow + rr * Dc);
        const int doff = which ? 256 : 0;

        __shared__ __align__(16) float sv[256];
        __shared__ float part[512];
        if (threadIdx.x < 256) sv[threadIdx.x] = src[threadIdx.x];
        __syncthreads();

        const int e    = threadIdx.x & 511;
        const int half = threadIdx.x >> 9;     // split-k: 2 threads per output
        const float4* a4 = (const float4*)sv + half * 32;
        const float4* w4 = (const float4*)(w + (size_t)e * Dc + doff) + half * 32;
        float acc = 0.f;
#pragma unroll 8
        for (int k = 0; k < 32; ++k) {
            float4 a = a4[k];
            float4 wb = w4[k];
            acc += a.x * wb.x + a.y * wb.y + a.z * wb.z + a.w * wb.w;
        }
        if (half) part[e] = acc;
        __syncthreads();
        if (!half) dst[e] = acc + part[e];
    }
}

// ---------------------------------------------------------------------------
// Dispatch 2: fused embed-add + LayerNorm. Round-5 structure (4 tokens/wave:
// (b0,b0+8) x (t,t+1)), with DENSE lane->element mapping: each lane owns two
// dense 4-float chunks, dLo = 4*lane in [0,256) and dHi = 256+4*lane. Every
// 16B vector load/store is now 64x16B CONTIGUOUS (1KB/instr) instead of the
// old d0=lane*8 layout where each float4 op touched 16B per 32B stride --
// 2x the 64B sectors per instruction across ALL loads and stores. That
// sector amplification (~36us of L1/TA traffic) is the theory for fuse_ln
// sitting at ~64us vs its ~25us streaming floor. Cached stores (round 2:
// NT amplifies HBM writes).
// ---------------------------------------------------------------------------
__global__ __launch_bounds__(256) void fuse_ln_kernel(
        const int* __restrict__ ids,
        const float* __restrict__ token_table, const float* __restrict__ pos_table,
        const float* __restrict__ gamma, const float* __restrict__ beta,
        float* __restrict__ out) {
    const int wave = threadIdx.x >> 6;
    const int lane = threadIdx.x & 63;
    const int g2 = blockIdx.x * 4 + wave;    // (t-pair, b0), b0 in [0,8)
    const int b0 = g2 & 7;
    const int t  = (g2 >> 3) << 1;           // even t; wave covers t, t+1
    const int idx00 = b0 * Tc + t;           // (b0,   t)
    const int idx10 = idx00 + 8 * Tc;        // (b0+8, t)
    const int dLo = lane * 4;                // dense low half  [0,256)
    const int dHi = 256 + lane * 4;          // dense high half [256,512)

    // token ids + packed coords: 8B vector loads, 2 tokens each
    const int2 tkA = *(const int2*)(ids + idx00);       // (b0,t), (b0,t+1)
    const int2 tkB = *(const int2*)(ids + idx10);       // (b0+8,t), (b0+8,t+1)
    const int2 pkA = *(const int2*)(g_packed + idx00);
    const int2 pkB = *(const int2*)(g_packed + idx10);

    // pos rows for t and t+1 (dense 1KB per instruction now)
    const float* pt = pos_table + (size_t)t * Dc;
    const fvec4 pLo0 = *(const fvec4*)(pt + dLo);
    const fvec4 pHi0 = *(const fvec4*)(pt + dHi);
    const fvec4 pLo1 = *(const fvec4*)(pt + Dc + dLo);
    const fvec4 pHi1 = *(const fvec4*)(pt + Dc + dHi);

    const fvec4 gmLo = *(const fvec4*)(gamma + dLo);
    const fvec4 gmHi = *(const fvec4*)(gamma + dHi);
    const fvec4 btLo = *(const fvec4*)(beta + dLo);
    const fvec4 btHi = *(const fvec4*)(beta + dHi);

    fvec4 xLo00, xHi00, xLo01, xHi01, xLo10, xHi10, xLo11, xHi11;

    auto load_tok = [&](int tok, fvec4 pl, fvec4 ph, fvec4& lo, fvec4& hi) {
        const float* tr = token_table + (size_t)tok * Dc;
        lo = *(const fvec4*)(tr + dLo) + pl;
        hi = *(const fvec4*)(tr + dHi) + ph;
    };
    load_tok(tkA.x, pLo0, pHi0, xLo00, xHi00);
    load_tok(tkA.y, pLo1, pHi1, xLo01, xHi01);
    load_tok(tkB.x, pLo0, pHi0, xLo10, xHi10);
    load_tok(tkB.y, pLo1, pHi1, xLo11, xHi11);

    auto add_spatial = [&](int tok, int pk, fvec4& lo, fvec4& hi) {
        if (tok <= 9) {                      // wave-uniform branch
            const int rI = pk >> 5, cI = pk & 31;
            const float* fr = g_frow + (size_t)rI * Dc;
            const float* fc = g_fcol + (size_t)cI * Dc;
            lo += *(const fvec4*)(fr + dLo) + *(const fvec4*)(fc + dLo);
            hi += *(const fvec4*)(fr + dHi) + *(const fvec4*)(fc + dHi);
        }
    };
    add_spatial(tkA.x, pkA.x, xLo00, xHi00);
    add_spatial(tkA.y, pkA.y, xLo01, xHi01);
    add_spatial(tkB.x, pkB.x, xLo10, xHi10);
    add_spatial(tkB.y, pkB.y, xLo11, xHi11);

    auto psum = [](fvec4 lo, fvec4 hi, float& s, float& q) {
        s = lo.x + lo.y + lo.z + lo.w + hi.x + hi.y + hi.z + hi.w;
        q = 0.f;
        q = fmaf(lo.x, lo.x, q); q = fmaf(lo.y, lo.y, q);
        q = fmaf(lo.z, lo.z, q); q = fmaf(lo.w, lo.w, q);
        q = fmaf(hi.x, hi.x, q); q = fmaf(hi.y, hi.y, q);
        q = fmaf(hi.z, hi.z, q); q = fmaf(hi.w, hi.w, q);
    };
    float s00, q00, s01, q01, s10, q10, s11, q11;
    psum(xLo00, xHi00, s00, q00);
    psum(xLo01, xHi01, s01, q01);
    psum(xLo10, xHi10, s10, q10);
    psum(xLo11, xHi11, s11, q11);

    // 8 independent butterfly chains interleaved
#pragma unroll
    for (int m = 1; m < 64; m <<= 1) {
        s00 += __shfl_xor(s00, m);
        s01 += __shfl_xor(s01, m);
        s10 += __shfl_xor(s10, m);
        s11 += __shfl_xor(s11, m);
        q00 += __shfl_xor(q00, m);
        q01 += __shfl_xor(q01, m);
        q10 += __shfl_xor(q10, m);
        q11 += __shfl_xor(q11, m);
    }

    const float mu00 = s00 * (1.0f / Dc);
    const float mu01 = s01 * (1.0f / Dc);
    const float mu10 = s10 * (1.0f / Dc);
    const float mu11 = s11 * (1.0f / Dc);
    const float inv00 = rsqrtf(fmaf(-mu00, mu00, q00 * (1.0f / Dc)) + 1e-5f);
    const float inv01 = rsqrtf(fmaf(-mu01, mu01, q01 * (1.0f / Dc)) + 1e-5f);
    const float inv10 = rsqrtf(fmaf(-mu10, mu10, q10 * (1.0f / Dc)) + 1e-5f);
    const float inv11 = rsqrtf(fmaf(-mu11, mu11, q11 * (1.0f / Dc)) + 1e-5f);

    auto store_row = [&](fvec4 lo, fvec4 hi, float mu, float inv, int base) {
        fvec4 yl = (lo - mu) * inv * gmLo + btLo;
        fvec4 yh = (hi - mu) * inv * gmHi + btHi;
        float* op = out + (size_t)base * Dc;
        *(fvec4*)(op + dLo) = yl;            // dense 1KB across the wave
        *(fvec4*)(op + dHi) = yh;            // dense 1KB across the wave
    };
    store_row(xLo00, xHi00, mu00, inv00, idx00);
    store_row(xLo01, xHi01, mu01, inv01, idx00 + 1);
    store_row(xLo10, xHi10, mu10, inv10, idx10);
    store_row(xLo11, xHi11, mu11, inv11, idx10 + 1);
}

extern "C" void kernel_launch(void* const* d_in, const int* in_sizes, int n_in,
                              void* d_out, int out_size, void* d_ws, size_t ws_size,
                              hipStream_t stream) {
    const int*   ids         = (const int*)d_in[0];
    const float* token_table = (const float*)d_in[1];
    const float* pos_table   = (const float*)d_in[2];
    const float* row_table   = (const float*)d_in[3];
    const float* col_table   = (const float*)d_in[4];
    const float* w_spatial   = (const float*)d_in[5];
    const float* ln_gamma    = (const float*)d_in[6];
    const float* ln_beta     = (const float*)d_in[7];
    float* out = (float*)d_out;

    (void)d_ws; (void)ws_size;   // ws poison is unconditional; we don't add to it

    hipLaunchKernelGGL(scan_pre_kernel, dim3(76), dim3(1024), 0, stream,
                       ids, row_table, col_table, w_spatial);
    hipLaunchKernelGGL(fuse_ln_kernel, dim3(Bc * Tc / 16), dim3(256), 0, stream,
                       ids, token_table, pos_table, ln_gamma, ln_beta, out);
}

// Round 9
// 175.440 us; speedup vs baseline: 1.2143x; 1.0651x over previous
//
#include <hip/hip_runtime.h>
#include <hip/hip_bf16.h>

constexpr int PAD_T = 10, BOS_T = 11, EOS_T = 12, ROW_T = 13, SEP_T = 14;
constexpr int Bc = 16, Tc = 4096, Dc = 512;
constexpr int MAXH = 30, MAXW = 30;

typedef float fvec4 __attribute__((ext_vector_type(4)));

// Scratch in module-scope device globals (the d_ws poison is unconditional,
// so d_ws is unused entirely). scan_pre_kernel fully rewrites all three
// every launch before fuse_ln_kernel reads them: no stale-data hazard.
__device__ __align__(16) int   g_packed[Bc * Tc];        // 256 KiB
__device__ __align__(16) float g_frow[MAXH * Dc];        // 60 KiB
__device__ __align__(16) float g_fcol[MAXW * Dc];        // 60 KiB

// Composable transition summary of a token chunk.
struct Summ { int r, c0, c1, g0, g1, rk, ck; };

__device__ inline void tok_update(int tok, Summ& s) {
    if (tok == BOS_T)      { s.g0 = 1; s.g1 = 1; s.r = 0; s.c0 = 0; s.c1 = 0; s.rk = 0; s.ck = 0; }
    else if (tok == SEP_T) { s.r = 0; s.c0 = 0; s.c1 = 0; s.rk = 0; s.ck = 0; }
    else if (tok == ROW_T) { s.r += 1; s.c0 = 0; s.c1 = 0; s.ck = 0; }
    else if (tok == EOS_T || tok == PAD_T) { s.g0 = 0; s.g1 = 0; }
    else { s.c0 += s.g0; s.c1 += s.g1; }   // digit 0..9
}

__device__ inline Summ compose(const Summ& a, const Summ& b) {
    Summ o;
    o.g0 = a.g0 ? b.g1 : b.g0;
    o.g1 = a.g1 ? b.g1 : b.g0;
    o.r  = b.rk ? a.r + b.r : b.r;
    o.rk = a.rk & b.rk;
    int cm0 = a.g0 ? b.c1 : b.c0;
    int cm1 = a.g1 ? b.c1 : b.c0;
    o.c0 = b.ck ? a.c0 + cm0 : cm0;
    o.c1 = b.ck ? a.c1 + cm1 : cm1;
    o.ck = a.ck & b.ck;
    return o;
}

__device__ inline void apply_state(const Summ& s, int& r, int& c, int& g) {
    int cm = g ? s.c1 : s.c0;
    r = s.rk ? r + s.r : s.r;
    c = s.ck ? c + cm : cm;
    g = g ? s.g1 : s.g0;
}

// ---------------------------------------------------------------------------
// Dispatch 1 (merged): blocks 0..15 = parallel automaton scan; blocks 16..75 =
// einsum collapse Frow = row_table @ W[:, :256]^T, Fcol = col_table @ W[:, 256:]^T.
// ---------------------------------------------------------------------------
__global__ __launch_bounds__(1024) void scan_pre_kernel(
        const int* __restrict__ ids,
        const float* __restrict__ row_table, const float* __restrict__ col_table,
        const float* __restrict__ w) {
    if (blockIdx.x < 16) {
        const int b = blockIdx.x;
        const int tid = threadIdx.x;          // 0..1023
        const int lane = tid & 63, wid = tid >> 6;

        const int4 tk4 = *(const int4*)(ids + b * Tc + tid * 4);
        int tks[4] = {tk4.x, tk4.y, tk4.z, tk4.w};

        Summ s{0, 0, 0, 0, 1, 1, 1};
#pragma unroll
        for (int j = 0; j < 4; ++j) tok_update(tks[j], s);

        Summ inc = s;
#pragma unroll
        for (int d = 1; d < 64; d <<= 1) {
            Summ o;
            o.r  = __shfl_up(inc.r, d);
            o.c0 = __shfl_up(inc.c0, d);
            o.c1 = __shfl_up(inc.c1, d);
            o.g0 = __shfl_up(inc.g0, d);
            o.g1 = __shfl_up(inc.g1, d);
            o.rk = __shfl_up(inc.rk, d);
            o.ck = __shfl_up(inc.ck, d);
            if (lane >= d) inc = compose(o, inc);
        }

        __shared__ int lsum[16][7];
        if (lane == 63) {
            lsum[wid][0] = inc.r;  lsum[wid][1] = inc.c0; lsum[wid][2] = inc.c1;
            lsum[wid][3] = inc.g0; lsum[wid][4] = inc.g1;
            lsum[wid][5] = inc.rk; lsum[wid][6] = inc.ck;
        }
        __syncthreads();

        int wr = 0, wc = 0, wg = 0;
        for (int w2 = 0; w2 < wid; ++w2) {
            Summ t;
            t.r  = lsum[w2][0]; t.c0 = lsum[w2][1]; t.c1 = lsum[w2][2];
            t.g0 = lsum[w2][3]; t.g1 = lsum[w2][4];
            t.rk = lsum[w2][5]; t.ck = lsum[w2][6];
            apply_state(t, wr, wc, wg);
        }

        Summ ex;
        ex.r  = __shfl_up(inc.r, 1);  ex.c0 = __shfl_up(inc.c0, 1);
        ex.c1 = __shfl_up(inc.c1, 1); ex.g0 = __shfl_up(inc.g0, 1);
        ex.g1 = __shfl_up(inc.g1, 1); ex.rk = __shfl_up(inc.rk, 1);
        ex.ck = __shfl_up(inc.ck, 1);
        if (lane == 0) { ex = Summ{0, 0, 0, 0, 1, 1, 1}; }
        int row = wr, col = wc, grid = wg;
        apply_state(ex, row, col, grid);

        int o4[4];
#pragma unroll
        for (int j = 0; j < 4; ++j) {
            int tok = tks[j];
            int gc = grid & (tok <= 9);
            int er = gc ? min(row, MAXH - 1) : 0;
            int ec = gc ? min(col, MAXW - 1) : 0;
            o4[j] = (er << 5) | ec;
            if (tok == BOS_T)      { grid = 1; row = 0; col = 0; }
            else if (tok == SEP_T) { row = 0; col = 0; }
            else if (tok == ROW_T) { row += 1; col = 0; }
            else if (tok == EOS_T || tok == PAD_T) { grid = 0; }
            else { col += gc; }
        }
        *(int4*)(g_packed + b * Tc + tid * 4) = make_int4(o4[0], o4[1], o4[2], o4[3]);
    } else {
        const int blk = blockIdx.x - 16;
        const int which = blk / 30;            // 0 -> Frow, 1 -> Fcol
        const int rr = blk % 30;
        const float* src = which ? (col_table + rr * 256) : (row_table + rr * 256);
        float* dst = which ? (g_fcol + rr * Dc) : (g_frow + rr * Dc);
        const int doff = which ? 256 : 0;

        __shared__ __align__(16) float sv[256];
        __shared__ float part[512];
        if (threadIdx.x < 256) sv[threadIdx.x] = src[threadIdx.x];
        __syncthreads();

        const int e    = threadIdx.x & 511;
        const int half = threadIdx.x >> 9;     // split-k: 2 threads per output
        const float4* a4 = (const float4*)sv + half * 32;
        const float4* w4 = (const float4*)(w + (size_t)e * Dc + doff) + half * 32;
        float acc = 0.f;
#pragma unroll 8
        for (int k = 0; k < 32; ++k) {
            float4 a = a4[k];
            float4 wb = w4[k];
            acc += a.x * wb.x + a.y * wb.y + a.z * wb.z + a.w * wb.w;
        }
        if (half) part[e] = acc;
        __syncthreads();
        if (!half) dst[e] = acc + part[e];
    }
}

// ---------------------------------------------------------------------------
// Dispatch 2: fused embed-add + LayerNorm. Round-8 body (4 tokens/wave,
// dense dLo/dHi lane mapping) with a STORE-LOCALITY wave mapping:
//   b0 = g >> 11 (slowest), tpair = g & 2047 (fastest)
// Consecutive waves of a block now write ADJACENT t of the same batch row
// (two contiguous 16KB runs per block; concurrent blocks cover contiguous
// address windows) instead of the old b-fastest mapping where concurrent
// waves scattered 2KB granules at 8MB stride across the 134MB output --
// DRAM row-buffer thrash that capped effective store rate at ~2.2TB/s
// (theory for fuse_ln's ~61us vs ~25us write floor). pos rows lose cross-b0
// concurrency-sharing (x4 refetch, ~32MB) but land in L3 after first touch.
// ids/packed reads also become streaming. Cached stores (round 2: NT
// amplifies partial-sector writes).
// ---------------------------------------------------------------------------
__global__ __launch_bounds__(256) void fuse_ln_kernel(
        const int* __restrict__ ids,
        const float* __restrict__ token_table, const float* __restrict__ pos_table,
        const float* __restrict__ gamma, const float* __restrict__ beta,
        float* __restrict__ out) {
    const int wave = threadIdx.x >> 6;
    const int lane = threadIdx.x & 63;
    const int g2 = blockIdx.x * 4 + wave;    // wave id in [0, 16384)
    const int b0 = g2 >> 11;                 // batch pair, SLOWEST (store locality)
    const int t  = (g2 & 2047) << 1;         // even t, FASTEST across waves
    const int idx00 = b0 * Tc + t;           // (b0,   t)
    const int idx10 = idx00 + 8 * Tc;        // (b0+8, t)
    const int dLo = lane * 4;                // dense low half  [0,256)
    const int dHi = 256 + lane * 4;          // dense high half [256,512)

    // token ids + packed coords: 8B vector loads, 2 tokens each
    const int2 tkA = *(const int2*)(ids + idx00);       // (b0,t), (b0,t+1)
    const int2 tkB = *(const int2*)(ids + idx10);       // (b0+8,t), (b0+8,t+1)
    const int2 pkA = *(const int2*)(g_packed + idx00);
    const int2 pkB = *(const int2*)(g_packed + idx10);

    // pos rows for t and t+1 (dense 1KB per instruction)
    const float* pt = pos_table + (size_t)t * Dc;
    const fvec4 pLo0 = *(const fvec4*)(pt + dLo);
    const fvec4 pHi0 = *(const fvec4*)(pt + dHi);
    const fvec4 pLo1 = *(const fvec4*)(pt + Dc + dLo);
    const fvec4 pHi1 = *(const fvec4*)(pt + Dc + dHi);

    const fvec4 gmLo = *(const fvec4*)(gamma + dLo);
    const fvec4 gmHi = *(const fvec4*)(gamma + dHi);
    const fvec4 btLo = *(const fvec4*)(beta + dLo);
    const fvec4 btHi = *(const fvec4*)(beta + dHi);

    fvec4 xLo00, xHi00, xLo01, xHi01, xLo10, xHi10, xLo11, xHi11;

    auto load_tok = [&](int tok, fvec4 pl, fvec4 ph, fvec4& lo, fvec4& hi) {
        const float* tr = token_table + (size_t)tok * Dc;
        lo = *(const fvec4*)(tr + dLo) + pl;
        hi = *(const fvec4*)(tr + dHi) + ph;
    };
    load_tok(tkA.x, pLo0, pHi0, xLo00, xHi00);
    load_tok(tkA.y, pLo1, pHi1, xLo01, xHi01);
    load_tok(tkB.x, pLo0, pHi0, xLo10, xHi10);
    load_tok(tkB.y, pLo1, pHi1, xLo11, xHi11);

    auto add_spatial = [&](int tok, int pk, fvec4& lo, fvec4& hi) {
        if (tok <= 9) {                      // wave-uniform branch
            const int rI = pk >> 5, cI = pk & 31;
            const float* fr = g_frow + (size_t)rI * Dc;
            const float* fc = g_fcol + (size_t)cI * Dc;
            lo += *(const fvec4*)(fr + dLo) + *(const fvec4*)(fc + dLo);
            hi += *(const fvec4*)(fr + dHi) + *(const fvec4*)(fc + dHi);
        }
    };
    add_spatial(tkA.x, pkA.x, xLo00, xHi00);
    add_spatial(tkA.y, pkA.y, xLo01, xHi01);
    add_spatial(tkB.x, pkB.x, xLo10, xHi10);
    add_spatial(tkB.y, pkB.y, xLo11, xHi11);

    auto psum = [](fvec4 lo, fvec4 hi, float& s, float& q) {
        s = lo.x + lo.y + lo.z + lo.w + hi.x + hi.y + hi.z + hi.w;
        q = 0.f;
        q = fmaf(lo.x, lo.x, q); q = fmaf(lo.y, lo.y, q);
        q = fmaf(lo.z, lo.z, q); q = fmaf(lo.w, lo.w, q);
        q = fmaf(hi.x, hi.x, q); q = fmaf(hi.y, hi.y, q);
        q = fmaf(hi.z, hi.z, q); q = fmaf(hi.w, hi.w, q);
    };
    float s00, q00, s01, q01, s10, q10, s11, q11;
    psum(xLo00, xHi00, s00, q00);
    psum(xLo01, xHi01, s01, q01);
    psum(xLo10, xHi10, s10, q10);
    psum(xLo11, xHi11, s11, q11);

    // 8 independent butterfly chains interleaved
#pragma unroll
    for (int m = 1; m < 64; m <<= 1) {
        s00 += __shfl_xor(s00, m);
        s01 += __shfl_xor(s01, m);
        s10 += __shfl_xor(s10, m);
        s11 += __shfl_xor(s11, m);
        q00 += __shfl_xor(q00, m);
        q01 += __shfl_xor(q01, m);
        q10 += __shfl_xor(q10, m);
        q11 += __shfl_xor(q11, m);
    }

    const float mu00 = s00 * (1.0f / Dc);
    const float mu01 = s01 * (1.0f / Dc);
    const float mu10 = s10 * (1.0f / Dc);
    const float mu11 = s11 * (1.0f / Dc);
    const float inv00 = rsqrtf(fmaf(-mu00, mu00, q00 * (1.0f / Dc)) + 1e-5f);
    const float inv01 = rsqrtf(fmaf(-mu01, mu01, q01 * (1.0f / Dc)) + 1e-5f);
    const float inv10 = rsqrtf(fmaf(-mu10, mu10, q10 * (1.0f / Dc)) + 1e-5f);
    const float inv11 = rsqrtf(fmaf(-mu11, mu11, q11 * (1.0f / Dc)) + 1e-5f);

    auto store_row = [&](fvec4 lo, fvec4 hi, float mu, float inv, int base) {
        fvec4 yl = (lo - mu) * inv * gmLo + btLo;
        fvec4 yh = (hi - mu) * inv * gmHi + btHi;
        float* op = out + (size_t)base * Dc;
        *(fvec4*)(op + dLo) = yl;            // dense 1KB across the wave
        *(fvec4*)(op + dHi) = yh;            // dense 1KB across the wave
    };
    store_row(xLo00, xHi00, mu00, inv00, idx00);
    store_row(xLo01, xHi01, mu01, inv01, idx00 + 1);
    store_row(xLo10, xHi10, mu10, inv10, idx10);
    store_row(xLo11, xHi11, mu11, inv11, idx10 + 1);
}

extern "C" void kernel_launch(void* const* d_in, const int* in_sizes, int n_in,
                              void* d_out, int out_size, void* d_ws, size_t ws_size,
                              hipStream_t stream) {
    const int*   ids         = (const int*)d_in[0];
    const float* token_table = (const float*)d_in[1];
    const float* pos_table   = (const float*)d_in[2];
    const float* row_table   = (const float*)d_in[3];
    const float* col_table   = (const float*)d_in[4];
    const float* w_spatial   = (const float*)d_in[5];
    const float* ln_gamma    = (const float*)d_in[6];
    const float* ln_beta     = (const float*)d_in[7];
    float* out = (float*)d_out;

    (void)d_ws; (void)ws_size;   // ws poison is unconditional; we don't add to it

    hipLaunchKernelGGL(scan_pre_kernel, dim3(76), dim3(1024), 0, stream,
                       ids, row_table, col_table, w_spatial);
    hipLaunchKernelGGL(fuse_ln_kernel, dim3(Bc * Tc / 16), dim3(256), 0, stream,
                       ids, token_table, pos_table, ln_gamma, ln_beta, out);
}